// Round 9
// baseline (200.170 us; speedup 1.0000x reference)
//
#include <hip/hip_runtime.h>

#define D_DIM 1024
#define B_HALF 4096
#define NROWS 8192
#define INV_TEMP 10.0f
#define NT2 64    // 8192 / 128 tiles per side
#define NKT 32    // 1024 / 32 K-tiles
#define NBLK 2080 // 64*65/2 upper-tri tiles

typedef __bf16 bf16x8 __attribute__((ext_vector_type(8)));
typedef float floatx4 __attribute__((ext_vector_type(4)));

#define MFMA16 __builtin_amdgcn_mfma_f32_16x16x32_bf16

__device__ __forceinline__ unsigned short f32_to_bf16(float f) {
    union { float f; unsigned u; } v; v.f = f;
    unsigned r = 0x7FFFu + ((v.u >> 16) & 1u);
    return (unsigned short)((v.u + r) >> 16);
}

// Kernel 1: L2-normalize rows of z1,z2 -> bf16 R [8192][1024]; zero S.
__global__ __launch_bounds__(256) void normalize_kernel(
    const float* __restrict__ z1, const float* __restrict__ z2,
    unsigned short* __restrict__ R, float* __restrict__ S)
{
    const int row = blockIdx.x;
    const int tid = threadIdx.x;
    const float* src = (row < B_HALF) ? (z1 + (size_t)row * D_DIM)
                                      : (z2 + (size_t)(row - B_HALF) * D_DIM);
    float4 v = ((const float4*)src)[tid];
    if (tid == 0) S[row] = 0.0f;
    float ss = v.x * v.x + v.y * v.y + v.z * v.z + v.w * v.w;
    #pragma unroll
    for (int off = 32; off > 0; off >>= 1) ss += __shfl_down(ss, off);
    __shared__ float wsum[4];
    if ((tid & 63) == 0) wsum[tid >> 6] = ss;
    __syncthreads();
    float tot = wsum[0] + wsum[1] + wsum[2] + wsum[3];
    float scale = 1.0f / fmaxf(sqrtf(tot), 1e-12f);
    ushort4 o;
    o.x = f32_to_bf16(v.x * scale);
    o.y = f32_to_bf16(v.y * scale);
    o.z = f32_to_bf16(v.z * scale);
    o.w = f32_to_bf16(v.w * scale);
    ((ushort4*)(R + (size_t)row * D_DIM))[tid] = o;
}

// Kernel 2: 128x128 upper-tri tiles, 4 waves (2x2), BK=32, DOUBLE-buffered
// 32 KiB LDS, one __syncthreads per K-tile; cross-block co-residency hides
// latency (m114). NATURAL dispatch order (no XCD remap — r8 measured it
// costs +30 MB FETCH); sqrt-seeded (rt,ct) decode. Conflict-free involution
// swizzle (r7/r8-measured 0 conflicts): global slot ^= (row>>1)&3 on the
// pre-swizzled gload source, same XOR on ds_read k-slot. Epilogue: row/col
// exp-sums reduced in LDS then atomically added into S.
__global__ __launch_bounds__(256) void gemm_lse_kernel(
    const unsigned short* __restrict__ R,
    float* __restrict__ S, float* __restrict__ pos)
{
    __shared__ unsigned short lds[2][2][128 * 32];   // [buf][A/B][row*32+e] 32 KiB

    // decode linear block id -> (rt, ct) with rt <= ct (rt-major), sqrt seed
    const int t = blockIdx.x;
    int rt = (int)((129.0f - sqrtf((float)(16641 - 8 * t))) * 0.5f);
    while ((rt + 1) * 64 - (rt + 1) * rt / 2 <= t) ++rt;   // fp-safety fixup
    while (rt * 64 - rt * (rt - 1) / 2 > t) --rt;
    const int ct = rt + (t - (rt * 64 - rt * (rt - 1) / 2));
    const bool isDiag = (rt == ct);

    const int tid = threadIdx.x;
    const int wave = tid >> 6, lane = tid & 63;
    const int wm = wave >> 1, wn = wave & 1;         // 2 x 2 wave grid
    const int row0 = rt * 128, col0 = ct * 128;
    const int lm = lane & 15, lq = lane >> 4;

    const unsigned short* __restrict__ gA = R + (size_t)row0 * D_DIM;
    const unsigned short* __restrict__ gB = R + (size_t)col0 * D_DIM;

    // staging: one issue = 64 lanes x 16B = 16 rows x 4 slots (1 KB), linear
    // LDS dest. Global slot pre-swizzled: s_g = (l&3) ^ ((row>>1)&3).
    const int sRow = lane >> 2;                      // 0..15
    const int sCol = (lane & 3) ^ ((sRow >> 1) & 3); // swizzled global 16B slot
    // read-side swizzled k-slot (row bits 1-2 == lm bits 1-2 for all frags)
    const int sk = (lq ^ ((lm >> 1) & 3)) * 8;
    const int aBase = lm * 32 + sk;
    const int bBase = lm * 32 + sk;

    floatx4 acc[4][4] = {};                          // 64 accumulators

#define STAGE(d, kk) \
    { _Pragma("unroll") for (int i = 0; i < 2; ++i) { \
        __builtin_amdgcn_global_load_lds( \
          (const __attribute__((address_space(1))) unsigned int*)(gA + (size_t)(wave * 32 + i * 16 + sRow) * D_DIM + (kk) + sCol * 8), \
          (__attribute__((address_space(3))) unsigned int*)(&lds[d][0][(wave * 32 + i * 16) * 32]), \
          16, 0, 0); \
        __builtin_amdgcn_global_load_lds( \
          (const __attribute__((address_space(1))) unsigned int*)(gB + (size_t)(wave * 32 + i * 16 + sRow) * D_DIM + (kk) + sCol * 8), \
          (__attribute__((address_space(3))) unsigned int*)(&lds[d][1][(wave * 32 + i * 16) * 32]), \
          16, 0, 0); \
      } }

    // prologue: stage K-tile 0 into buf 0
    STAGE(0, 0)
    __syncthreads();

    for (int kt = 0; kt < NKT; ++kt) {
        const int buf = kt & 1;
        const unsigned short* As = &lds[buf][0][0];
        const unsigned short* Bs = &lds[buf][1][0];

        if (kt + 1 < NKT) STAGE(buf ^ 1, (kt + 1) * 32)

        bf16x8 af[4], bf[4];
        #pragma unroll
        for (int i = 0; i < 4; ++i) {
            af[i] = *(const bf16x8*)(As + (wm * 64 + i * 16) * 32 + aBase);
            bf[i] = *(const bf16x8*)(Bs + (wn * 64 + i * 16) * 32 + bBase);
        }
        #pragma unroll
        for (int mi = 0; mi < 4; ++mi)
            #pragma unroll
            for (int ni = 0; ni < 4; ++ni)
                acc[mi][ni] = MFMA16(af[mi], bf[ni], acc[mi][ni], 0, 0, 0);

        __syncthreads();   // drains vmcnt (next tile landed) + protects dbuf
    }

    // Epilogue: staging LDS dead -> overlay sums; reduce then atomic into S.
    float* rowsum = (float*)&lds[0][0][0];   // [2][128]
    float* colsum = rowsum + 2 * 128;        // [2][128]

    float ecol[4] = {0.0f, 0.0f, 0.0f, 0.0f};
    #pragma unroll
    for (int mi = 0; mi < 4; ++mi) {
        const int rloc = wm * 64 + mi * 16 + lq * 4;
        #pragma unroll
        for (int reg = 0; reg < 4; ++reg) {
            const int gr = row0 + rloc + reg;
            float esum = 0.0f;
            #pragma unroll
            for (int ni = 0; ni < 4; ++ni) {
                const int gc = col0 + wn * 64 + ni * 16 + lm;
                float s = acc[mi][ni][reg] * INV_TEMP;
                if (gc == gr + B_HALF) { pos[gr] = s; pos[gc] = s; }
                float e = (gc == gr) ? 0.0f : __expf(s);
                esum += e;
                ecol[ni] += e;
            }
            esum += __shfl_xor(esum, 1);
            esum += __shfl_xor(esum, 2);
            esum += __shfl_xor(esum, 4);
            esum += __shfl_xor(esum, 8);
            if (lm == 0) rowsum[wn * 128 + rloc + reg] = esum;
        }
    }
    #pragma unroll
    for (int ni = 0; ni < 4; ++ni) {
        ecol[ni] += __shfl_xor(ecol[ni], 16);
        ecol[ni] += __shfl_xor(ecol[ni], 32);
    }
    if (lq == 0 && !isDiag) {
        #pragma unroll
        for (int ni = 0; ni < 4; ++ni)
            colsum[wm * 128 + wn * 64 + ni * 16 + lm] = ecol[ni];
    }
    __syncthreads();
    if (tid < 128) {
        float rs = rowsum[tid] + rowsum[128 + tid];
        atomicAdd(&S[row0 + tid], rs);
        if (!isDiag) {
            float cs = colsum[tid] + colsum[128 + tid];
            atomicAdd(&S[col0 + tid], cs);
        }
    }
}

// Kernel 3: single block; loss = mean(log1p(S * exp(-pos))).
__global__ __launch_bounds__(1024) void finalize_kernel(
    const float* __restrict__ S, const float* __restrict__ pos,
    float* __restrict__ out)
{
    const int tid = threadIdx.x;
    float local = 0.0f;
    #pragma unroll
    for (int i = 0; i < 8; ++i) {
        const int r = i * 1024 + tid;
        local += log1pf(S[r] * __expf(-pos[r]));
    }
    #pragma unroll
    for (int off = 32; off > 0; off >>= 1) local += __shfl_down(local, off);
    __shared__ float ws[16];
    if ((tid & 63) == 0) ws[tid >> 6] = local;
    __syncthreads();
    if (tid == 0) {
        float tot = 0.0f;
        #pragma unroll
        for (int i = 0; i < 16; ++i) tot += ws[i];
        out[0] = tot * (1.0f / 8192.0f);
    }
}

extern "C" void kernel_launch(void* const* d_in, const int* in_sizes, int n_in,
                              void* d_out, int out_size, void* d_ws, size_t ws_size,
                              hipStream_t stream)
{
    const float* z1 = (const float*)d_in[0];
    const float* z2 = (const float*)d_in[1];
    float* out = (float*)d_out;
    char* ws = (char*)d_ws;
    unsigned short* R = (unsigned short*)ws;                        // 16 MiB bf16 reps
    float* pos = (float*)(ws + (size_t)16 * 1024 * 1024);           // 32 KiB [8192]
    float* S   = (float*)(ws + (size_t)16 * 1024 * 1024 + 65536);   // 32 KiB [8192]

    normalize_kernel<<<NROWS, 256, 0, stream>>>(z1, z2, R, S);
    gemm_lse_kernel<<<NBLK, 256, 0, stream>>>(R, S, pos);
    finalize_kernel<<<1, 1024, 0, stream>>>(S, pos, out);
}

// Round 10
// 164.340 us; speedup vs baseline: 1.2180x; 1.2180x over previous
//
#include <hip/hip_runtime.h>

#define D_DIM 1024
#define B_HALF 4096
#define NROWS 8192
#define INV_TEMP 10.0f
#define NKT 32      // 1024 / 32 K-tiles
#define NBIG 512    // 528 upper-tri 256-tiles minus the 16 (rt, rt+16) tiles
#define NBLK 576    // + 64 quadrant 128-tiles dispatched last

typedef __bf16 bf16x8 __attribute__((ext_vector_type(8)));
typedef float floatx4 __attribute__((ext_vector_type(4)));

#define MFMA16 __builtin_amdgcn_mfma_f32_16x16x32_bf16
#define AS1 const __attribute__((address_space(1))) unsigned int*
#define AS3 __attribute__((address_space(3))) unsigned int*

__device__ __forceinline__ unsigned short f32_to_bf16(float f) {
    union { float f; unsigned u; } v; v.f = f;
    unsigned r = 0x7FFFu + ((v.u >> 16) & 1u);
    return (unsigned short)((v.u + r) >> 16);
}

// Kernel 1: wave-per-row L2-normalize (no barriers, no LDS). 2048 blocks x
// 4 waves; each 64-lane wave owns one row (64 x float4 = 1024 elems).
__global__ __launch_bounds__(256) void normalize_kernel(
    const float* __restrict__ z1, const float* __restrict__ z2,
    unsigned short* __restrict__ R, float* __restrict__ S)
{
    const int tid = threadIdx.x;
    const int lane = tid & 63;
    const int row = blockIdx.x * 4 + (tid >> 6);
    const float* src = (row < B_HALF) ? (z1 + (size_t)row * D_DIM)
                                      : (z2 + (size_t)(row - B_HALF) * D_DIM);
    float4 v = ((const float4*)src)[lane];
    if (lane == 0) S[row] = 0.0f;
    float ss = v.x * v.x + v.y * v.y + v.z * v.z + v.w * v.w;
    ss += __shfl_xor(ss, 1);
    ss += __shfl_xor(ss, 2);
    ss += __shfl_xor(ss, 4);
    ss += __shfl_xor(ss, 8);
    ss += __shfl_xor(ss, 16);
    ss += __shfl_xor(ss, 32);
    float scale = 1.0f / fmaxf(sqrtf(ss), 1e-12f);
    ushort4 o;
    o.x = f32_to_bf16(v.x * scale);
    o.y = f32_to_bf16(v.y * scale);
    o.z = f32_to_bf16(v.z * scale);
    o.w = f32_to_bf16(v.w * scale);
    ((ushort4*)(R + (size_t)row * D_DIM))[lane] = o;
}

// Kernel 2, mixed grid:
//  blocks [0,512): 256x256 upper-tri tiles EXCLUDING the 16 (rt, rt+16)
//    pos-band tiles (hole-skip decode). r2-verified K-loop: 8 waves (2Mx4N),
//    BK=32, double-buffered 64 KiB LDS, one vmcnt(0)+barrier per K-tile,
//    involution swizzle (slot ^= (row>>1)&3, zero conflicts measured).
//  blocks [512,576): the 16 removed tiles split into 64 128x128 quadrants
//    (never diagonal; carry all pos pairs), dispatched LAST -> cheap 3rd
//    round backfill (~1/4 block time).
//  Epilogue (both): row/col exp-sums reduced in LDS, atomicAdd into S.
__global__ __launch_bounds__(512, 2) void gemm_lse_kernel(
    const unsigned short* __restrict__ R,
    float* __restrict__ S, float* __restrict__ pos)
{
    __shared__ unsigned short lds[2][2][256 * 32];   // 64 KiB

    const int tid = threadIdx.x;
    const int wave = tid >> 6, lane = tid & 63;
    const int lm = lane & 15, lq = lane >> 4;
    const int wm = wave >> 2, wn = wave & 3;         // 2 x 4 wave grid
    // staging lane map: 16 rows x 4 slots per issue; involution swizzle
    const int sRow = lane >> 2;                      // 0..15
    const int sCol = (lane & 3) ^ ((sRow >> 1) & 3); // swizzled global slot
    const int sk = (lq ^ ((lm >> 1) & 3)) * 8;       // swizzled read k-slot

    if (blockIdx.x < NBIG) {
        // ---- BIG PATH: 256x256 ----
        int t = blockIdx.x;
        #pragma unroll
        for (int i = 0; i < 16; ++i) {               // skip the 16 holes
            const int h = 32 * i - (i * (i - 1)) / 2 + 16;
            if (t >= h) ++t;
        }
        int rt = 0;
        while (t >= 32 - rt) { t -= 32 - rt; ++rt; }
        const int ct = rt + t;
        const bool isDiag = (rt == ct);
        const int row0 = rt * 256, col0 = ct * 256;

        const unsigned short* __restrict__ gA = R + (size_t)row0 * D_DIM;
        const unsigned short* __restrict__ gB = R + (size_t)col0 * D_DIM;
        const int aBase = (wm * 128 + lm) * 32 + sk;
        const int bBase = (wn * 64 + lm) * 32 + sk;

        floatx4 acc[8][4] = {};

#define BSTAGE(d, kk) \
        { _Pragma("unroll") for (int i = 0; i < 2; ++i) { \
            __builtin_amdgcn_global_load_lds( \
              (AS1)(gA + (size_t)(wave * 32 + i * 16 + sRow) * D_DIM + (kk) + sCol * 8), \
              (AS3)(&lds[d][0][(wave * 32 + i * 16) * 32]), 16, 0, 0); \
            __builtin_amdgcn_global_load_lds( \
              (AS1)(gB + (size_t)(wave * 32 + i * 16 + sRow) * D_DIM + (kk) + sCol * 8), \
              (AS3)(&lds[d][1][(wave * 32 + i * 16) * 32]), 16, 0, 0); } }

        BSTAGE(0, 0)
        asm volatile("s_waitcnt vmcnt(0)" ::: "memory");
        __builtin_amdgcn_s_barrier();

        for (int kt = 0; kt < NKT; ++kt) {
            const int buf = kt & 1;
            const unsigned short* As = &lds[buf][0][0];
            const unsigned short* Bs = &lds[buf][1][0];
            if (kt + 1 < NKT) BSTAGE(buf ^ 1, (kt + 1) * 32)

            bf16x8 af[8], bf[4];
            #pragma unroll
            for (int mi = 0; mi < 8; ++mi)
                af[mi] = *(const bf16x8*)(As + aBase + mi * 512);
            #pragma unroll
            for (int ni = 0; ni < 4; ++ni)
                bf[ni] = *(const bf16x8*)(Bs + bBase + ni * 512);

            __builtin_amdgcn_s_setprio(1);
            #pragma unroll
            for (int mi = 0; mi < 8; ++mi)
                #pragma unroll
                for (int ni = 0; ni < 4; ++ni)
                    acc[mi][ni] = MFMA16(af[mi], bf[ni], acc[mi][ni], 0, 0, 0);
            __builtin_amdgcn_s_setprio(0);

            asm volatile("s_waitcnt vmcnt(0)" ::: "memory");
            __builtin_amdgcn_s_barrier();
        }

        float* rowsum = (float*)&lds[0][0][0];   // [4][256]
        float* colsum = rowsum + 4 * 256;        // [2][256]
        float ecol[4] = {0.0f, 0.0f, 0.0f, 0.0f};
        #pragma unroll
        for (int mi = 0; mi < 8; ++mi) {
            const int rloc = wm * 128 + mi * 16 + lq * 4;
            #pragma unroll
            for (int reg = 0; reg < 4; ++reg) {
                const int gr = row0 + rloc + reg;
                float esum = 0.0f;
                #pragma unroll
                for (int ni = 0; ni < 4; ++ni) {
                    const int gc = col0 + wn * 64 + ni * 16 + lm;
                    float s = acc[mi][ni][reg] * INV_TEMP;
                    if (gc == gr + B_HALF) { pos[gr] = s; pos[gc] = s; }
                    float e = (gc == gr) ? 0.0f : __expf(s);
                    esum += e;
                    ecol[ni] += e;
                }
                esum += __shfl_xor(esum, 1);
                esum += __shfl_xor(esum, 2);
                esum += __shfl_xor(esum, 4);
                esum += __shfl_xor(esum, 8);
                if (lm == 0) rowsum[wn * 256 + rloc + reg] = esum;
            }
        }
        #pragma unroll
        for (int ni = 0; ni < 4; ++ni) {
            ecol[ni] += __shfl_xor(ecol[ni], 16);
            ecol[ni] += __shfl_xor(ecol[ni], 32);
        }
        if (lq == 0 && !isDiag) {
            #pragma unroll
            for (int ni = 0; ni < 4; ++ni)
                colsum[wm * 256 + wn * 64 + ni * 16 + lm] = ecol[ni];
        }
        __syncthreads();
        if (tid < 256) {
            float rs = rowsum[tid] + rowsum[256 + tid]
                     + rowsum[512 + tid] + rowsum[768 + tid];
            atomicAdd(&S[row0 + tid], rs);
            if (!isDiag) {
                float cs = colsum[tid] + colsum[256 + tid];
                atomicAdd(&S[col0 + tid], cs);
            }
        }
    } else {
        // ---- SMALL PATH: 128x128 quadrants of the 16 (rt, rt+16) tiles ----
        const int s = blockIdx.x - NBIG;
        const int p = s >> 2, qr = (s >> 1) & 1, qc = s & 1;
        const int row0 = (2 * p + qr) * 128;
        const int col0 = (2 * p + 32 + qc) * 128;   // never diagonal

        const unsigned short* __restrict__ gA = R + (size_t)row0 * D_DIM;
        const unsigned short* __restrict__ gB = R + (size_t)col0 * D_DIM;
        const int aBase = (wm * 64 + lm) * 32 + sk;
        const int bBase = (wn * 32 + lm) * 32 + sk;

        floatx4 acc[4][2] = {};

#define SSTAGE(d, kk) \
        { __builtin_amdgcn_global_load_lds( \
            (AS1)(gA + (size_t)(wave * 16 + sRow) * D_DIM + (kk) + sCol * 8), \
            (AS3)(&lds[d][0][(wave * 16) * 32]), 16, 0, 0); \
          __builtin_amdgcn_global_load_lds( \
            (AS1)(gB + (size_t)(wave * 16 + sRow) * D_DIM + (kk) + sCol * 8), \
            (AS3)(&lds[d][1][(wave * 16) * 32]), 16, 0, 0); }

        SSTAGE(0, 0)
        asm volatile("s_waitcnt vmcnt(0)" ::: "memory");
        __builtin_amdgcn_s_barrier();

        for (int kt = 0; kt < NKT; ++kt) {
            const int buf = kt & 1;
            const unsigned short* As = &lds[buf][0][0];
            const unsigned short* Bs = &lds[buf][1][0];
            if (kt + 1 < NKT) SSTAGE(buf ^ 1, (kt + 1) * 32)

            bf16x8 af[4], bf[2];
            #pragma unroll
            for (int mi = 0; mi < 4; ++mi)
                af[mi] = *(const bf16x8*)(As + aBase + mi * 512);
            #pragma unroll
            for (int ni = 0; ni < 2; ++ni)
                bf[ni] = *(const bf16x8*)(Bs + bBase + ni * 512);

            __builtin_amdgcn_s_setprio(1);
            #pragma unroll
            for (int mi = 0; mi < 4; ++mi)
                #pragma unroll
                for (int ni = 0; ni < 2; ++ni)
                    acc[mi][ni] = MFMA16(af[mi], bf[ni], acc[mi][ni], 0, 0, 0);
            __builtin_amdgcn_s_setprio(0);

            asm volatile("s_waitcnt vmcnt(0)" ::: "memory");
            __builtin_amdgcn_s_barrier();
        }

        float* rowsum = (float*)&lds[0][0][0];   // [4][128]
        float* colsum = rowsum + 4 * 128;        // [2][128]
        float ecol[2] = {0.0f, 0.0f};
        #pragma unroll
        for (int mi = 0; mi < 4; ++mi) {
            const int rloc = wm * 64 + mi * 16 + lq * 4;
            #pragma unroll
            for (int reg = 0; reg < 4; ++reg) {
                const int gr = row0 + rloc + reg;
                float esum = 0.0f;
                #pragma unroll
                for (int ni = 0; ni < 2; ++ni) {
                    const int gc = col0 + wn * 32 + ni * 16 + lm;
                    float s = acc[mi][ni][reg] * INV_TEMP;
                    if (gc == gr + B_HALF) { pos[gr] = s; pos[gc] = s; }
                    float e = __expf(s);     // never on the main diagonal
                    esum += e;
                    ecol[ni] += e;
                }
                esum += __shfl_xor(esum, 1);
                esum += __shfl_xor(esum, 2);
                esum += __shfl_xor(esum, 4);
                esum += __shfl_xor(esum, 8);
                if (lm == 0) rowsum[wn * 128 + rloc + reg] = esum;
            }
        }
        #pragma unroll
        for (int ni = 0; ni < 2; ++ni) {
            ecol[ni] += __shfl_xor(ecol[ni], 16);
            ecol[ni] += __shfl_xor(ecol[ni], 32);
        }
        if (lq == 0) {
            #pragma unroll
            for (int ni = 0; ni < 2; ++ni)
                colsum[wm * 128 + wn * 32 + ni * 16 + lm] = ecol[ni];
        }
        __syncthreads();
        if (tid < 128) {
            float rs = rowsum[tid] + rowsum[128 + tid]
                     + rowsum[256 + tid] + rowsum[384 + tid];
            atomicAdd(&S[row0 + tid], rs);
            float cs = colsum[tid] + colsum[128 + tid];
            atomicAdd(&S[col0 + tid], cs);
        }
    }
}

// Kernel 3: single block; loss = mean(log1p(S * exp(-pos))).
__global__ __launch_bounds__(1024) void finalize_kernel(
    const float* __restrict__ S, const float* __restrict__ pos,
    float* __restrict__ out)
{
    const int tid = threadIdx.x;
    float local = 0.0f;
    #pragma unroll
    for (int i = 0; i < 8; ++i) {
        const int r = i * 1024 + tid;
        local += log1pf(S[r] * __expf(-pos[r]));
    }
    #pragma unroll
    for (int off = 32; off > 0; off >>= 1) local += __shfl_down(local, off);
    __shared__ float ws[16];
    if ((tid & 63) == 0) ws[tid >> 6] = local;
    __syncthreads();
    if (tid == 0) {
        float tot = 0.0f;
        #pragma unroll
        for (int i = 0; i < 16; ++i) tot += ws[i];
        out[0] = tot * (1.0f / 8192.0f);
    }
}

extern "C" void kernel_launch(void* const* d_in, const int* in_sizes, int n_in,
                              void* d_out, int out_size, void* d_ws, size_t ws_size,
                              hipStream_t stream)
{
    const float* z1 = (const float*)d_in[0];
    const float* z2 = (const float*)d_in[1];
    float* out = (float*)d_out;
    char* ws = (char*)d_ws;
    unsigned short* R = (unsigned short*)ws;                        // 16 MiB bf16 reps
    float* pos = (float*)(ws + (size_t)16 * 1024 * 1024);           // 32 KiB [8192]
    float* S   = (float*)(ws + (size_t)16 * 1024 * 1024 + 65536);   // 32 KiB [8192]

    normalize_kernel<<<2048, 256, 0, stream>>>(z1, z2, R, S);
    gemm_lse_kernel<<<NBLK, 512, 0, stream>>>(R, S, pos);
    finalize_kernel<<<1, 1024, 0, stream>>>(S, pos, out);
}

// Round 11
// 162.032 us; speedup vs baseline: 1.2354x; 1.0142x over previous
//
#include <hip/hip_runtime.h>

#define D_DIM 1024
#define B_HALF 4096
#define NROWS 8192
#define INV_TEMP 10.0f
#define NKT64 16    // 1024 / 64 K-tiles
#define NBIG 512    // 528 upper-tri 256-tiles minus the 16 (rt, rt+16) tiles
#define NBLK 576    // + 64 quadrant 128-tiles dispatched last

typedef __bf16 bf16x8 __attribute__((ext_vector_type(8)));
typedef float floatx4 __attribute__((ext_vector_type(4)));

#define MFMA16 __builtin_amdgcn_mfma_f32_16x16x32_bf16
#define AS1 const __attribute__((address_space(1))) unsigned int*
#define AS3 __attribute__((address_space(3))) unsigned int*

__device__ __forceinline__ unsigned short f32_to_bf16(float f) {
    union { float f; unsigned u; } v; v.f = f;
    unsigned r = 0x7FFFu + ((v.u >> 16) & 1u);
    return (unsigned short)((v.u + r) >> 16);
}

// Kernel 1: wave-per-row L2-normalize. Each 64-lane wave owns one FULL row:
// 4 x float4 per lane (64*16 = 1024 elems). No barriers, no LDS.
__global__ __launch_bounds__(256) void normalize_kernel(
    const float* __restrict__ z1, const float* __restrict__ z2,
    unsigned short* __restrict__ R, float* __restrict__ S)
{
    const int tid = threadIdx.x;
    const int lane = tid & 63;
    const int row = blockIdx.x * 4 + (tid >> 6);
    const float* src = (row < B_HALF) ? (z1 + (size_t)row * D_DIM)
                                      : (z2 + (size_t)(row - B_HALF) * D_DIM);
    const float4* s4 = (const float4*)src;
    float4 v0 = s4[lane], v1 = s4[64 + lane], v2 = s4[128 + lane], v3 = s4[192 + lane];
    if (lane == 0) S[row] = 0.0f;
    float ss = v0.x*v0.x + v0.y*v0.y + v0.z*v0.z + v0.w*v0.w
             + v1.x*v1.x + v1.y*v1.y + v1.z*v1.z + v1.w*v1.w
             + v2.x*v2.x + v2.y*v2.y + v2.z*v2.z + v2.w*v2.w
             + v3.x*v3.x + v3.y*v3.y + v3.z*v3.z + v3.w*v3.w;
    ss += __shfl_xor(ss, 1);
    ss += __shfl_xor(ss, 2);
    ss += __shfl_xor(ss, 4);
    ss += __shfl_xor(ss, 8);
    ss += __shfl_xor(ss, 16);
    ss += __shfl_xor(ss, 32);
    float scale = 1.0f / fmaxf(sqrtf(ss), 1e-12f);
    ushort4* dst = (ushort4*)(R + (size_t)row * D_DIM);
    float4 vv[4] = {v0, v1, v2, v3};
    #pragma unroll
    for (int i = 0; i < 4; ++i) {
        ushort4 o;
        o.x = f32_to_bf16(vv[i].x * scale);
        o.y = f32_to_bf16(vv[i].y * scale);
        o.z = f32_to_bf16(vv[i].z * scale);
        o.w = f32_to_bf16(vv[i].w * scale);
        dst[i * 64 + lane] = o;
    }
}

// Kernel 2, mixed grid (r10-verified makespan win):
//  blocks [0,512): 256x256 upper-tri tiles excluding the 16 (rt, rt+16)
//    pos-band tiles. BK=64 double-buffered 128 KiB LDS, ONE vmcnt(0)+barrier
//    per K-tile (16 drain events vs 32 at BK=32). Involution swizzle
//    slot ^= row&7 (r5-measured ZERO conflicts at this exact geometry).
//  blocks [512,576): the 16 removed tiles as 64 128x128 quadrants
//    (never diagonal; carry all pos pairs), dispatched last (backfill).
//  Epilogue: row/col exp-sums reduced in LDS, atomicAdd into S.
__global__ __launch_bounds__(512, 2) void gemm_lse_kernel(
    const unsigned short* __restrict__ R,
    float* __restrict__ S, float* __restrict__ pos)
{
    __shared__ unsigned short lds[2][2][256 * 64];   // 128 KiB

    const int tid = threadIdx.x;
    const int wave = tid >> 6, lane = tid & 63;
    const int lm = lane & 15, lq = lane >> 4;
    const int wm = wave >> 2, wn = wave & 3;         // 2 x 4 wave grid
    // staging lane map: one issue = 8 rows x 8 slots (1 KB), linear LDS dest;
    // global slot pre-swizzled: s_g = (l&7) ^ (row&7)   [involution]
    const int sR8 = lane >> 3;                       // 0..7
    const int sS8 = (lane & 7) ^ sR8;
    // read-side swizzled k-slots (row&7 == lm&7 for all frag rows)
    const int sk0 = ((0 + lq) ^ (lm & 7)) * 8;
    const int sk1 = ((4 + lq) ^ (lm & 7)) * 8;

    if (blockIdx.x < NBIG) {
        // ---- BIG PATH: 256x256, BK=64 ----
        int t = blockIdx.x;
        #pragma unroll
        for (int i = 0; i < 16; ++i) {               // skip the 16 holes
            const int h = 32 * i - (i * (i - 1)) / 2 + 16;
            if (t >= h) ++t;
        }
        int rt = 0;
        while (t >= 32 - rt) { t -= 32 - rt; ++rt; }
        const int ct = rt + t;
        const bool isDiag = (rt == ct);
        const int row0 = rt * 256, col0 = ct * 256;

        const unsigned short* __restrict__ gA = R + (size_t)row0 * D_DIM;
        const unsigned short* __restrict__ gB = R + (size_t)col0 * D_DIM;

        floatx4 acc[8][4] = {};

#define BSTAGE(d, kk) \
        { _Pragma("unroll") for (int i = 0; i < 4; ++i) { \
            __builtin_amdgcn_global_load_lds( \
              (AS1)(gA + (size_t)(wave * 32 + i * 8 + sR8) * D_DIM + (kk) + sS8 * 8), \
              (AS3)(&lds[d][0][(wave * 32 + i * 8) * 64]), 16, 0, 0); \
            __builtin_amdgcn_global_load_lds( \
              (AS1)(gB + (size_t)(wave * 32 + i * 8 + sR8) * D_DIM + (kk) + sS8 * 8), \
              (AS3)(&lds[d][1][(wave * 32 + i * 8) * 64]), 16, 0, 0); } }

        BSTAGE(0, 0)
        asm volatile("s_waitcnt vmcnt(0)" ::: "memory");
        __builtin_amdgcn_s_barrier();

        for (int kt = 0; kt < NKT64; ++kt) {
            const int buf = kt & 1;
            const unsigned short* As = &lds[buf][0][0];
            const unsigned short* Bs = &lds[buf][1][0];
            if (kt + 1 < NKT64) BSTAGE(buf ^ 1, (kt + 1) * 64)

            bf16x8 bf[4][2], af[4][2];
            #pragma unroll
            for (int ni = 0; ni < 4; ++ni) {
                const int r = (wn * 64 + ni * 16 + lm) * 64;
                bf[ni][0] = *(const bf16x8*)(Bs + r + sk0);
                bf[ni][1] = *(const bf16x8*)(Bs + r + sk1);
            }
            #pragma unroll
            for (int mi = 0; mi < 4; ++mi) {
                const int r = (wm * 128 + mi * 16 + lm) * 64;
                af[mi][0] = *(const bf16x8*)(As + r + sk0);
                af[mi][1] = *(const bf16x8*)(As + r + sk1);
            }
            __builtin_amdgcn_s_setprio(1);
            #pragma unroll
            for (int mi = 0; mi < 4; ++mi)
                #pragma unroll
                for (int ni = 0; ni < 4; ++ni) {
                    acc[mi][ni] = MFMA16(af[mi][0], bf[ni][0], acc[mi][ni], 0, 0, 0);
                    acc[mi][ni] = MFMA16(af[mi][1], bf[ni][1], acc[mi][ni], 0, 0, 0);
                }
            __builtin_amdgcn_s_setprio(0);
            #pragma unroll
            for (int mi = 0; mi < 4; ++mi) {
                const int r = (wm * 128 + (4 + mi) * 16 + lm) * 64;
                af[mi][0] = *(const bf16x8*)(As + r + sk0);
                af[mi][1] = *(const bf16x8*)(As + r + sk1);
            }
            __builtin_amdgcn_s_setprio(1);
            #pragma unroll
            for (int mi = 0; mi < 4; ++mi)
                #pragma unroll
                for (int ni = 0; ni < 4; ++ni) {
                    acc[4 + mi][ni] = MFMA16(af[mi][0], bf[ni][0], acc[4 + mi][ni], 0, 0, 0);
                    acc[4 + mi][ni] = MFMA16(af[mi][1], bf[ni][1], acc[4 + mi][ni], 0, 0, 0);
                }
            __builtin_amdgcn_s_setprio(0);

            asm volatile("s_waitcnt vmcnt(0)" ::: "memory");
            __builtin_amdgcn_s_barrier();
        }

        float* rowsum = (float*)&lds[0][0][0];   // [4][256]
        float* colsum = rowsum + 4 * 256;        // [2][256]
        float ecol[4] = {0.0f, 0.0f, 0.0f, 0.0f};
        #pragma unroll
        for (int mi = 0; mi < 8; ++mi) {
            const int rloc = wm * 128 + mi * 16 + lq * 4;
            #pragma unroll
            for (int reg = 0; reg < 4; ++reg) {
                const int gr = row0 + rloc + reg;
                float esum = 0.0f;
                #pragma unroll
                for (int ni = 0; ni < 4; ++ni) {
                    const int gc = col0 + wn * 64 + ni * 16 + lm;
                    float s = acc[mi][ni][reg] * INV_TEMP;
                    if (gc == gr + B_HALF) { pos[gr] = s; pos[gc] = s; }
                    float e = (gc == gr) ? 0.0f : __expf(s);
                    esum += e;
                    ecol[ni] += e;
                }
                esum += __shfl_xor(esum, 1);
                esum += __shfl_xor(esum, 2);
                esum += __shfl_xor(esum, 4);
                esum += __shfl_xor(esum, 8);
                if (lm == 0) rowsum[wn * 256 + rloc + reg] = esum;
            }
        }
        #pragma unroll
        for (int ni = 0; ni < 4; ++ni) {
            ecol[ni] += __shfl_xor(ecol[ni], 16);
            ecol[ni] += __shfl_xor(ecol[ni], 32);
        }
        if (lq == 0 && !isDiag) {
            #pragma unroll
            for (int ni = 0; ni < 4; ++ni)
                colsum[wm * 256 + wn * 64 + ni * 16 + lm] = ecol[ni];
        }
        __syncthreads();
        if (tid < 256) {
            float rs = rowsum[tid] + rowsum[256 + tid]
                     + rowsum[512 + tid] + rowsum[768 + tid];
            atomicAdd(&S[row0 + tid], rs);
            if (!isDiag) {
                float cs = colsum[tid] + colsum[256 + tid];
                atomicAdd(&S[col0 + tid], cs);
            }
        }
    } else {
        // ---- SMALL PATH: 128x128 quadrants of the 16 (rt, rt+16) tiles ----
        const int s = blockIdx.x - NBIG;
        const int p = s >> 2, qr = (s >> 1) & 1, qc = s & 1;
        const int row0 = (2 * p + qr) * 128;
        const int col0 = (2 * p + 32 + qc) * 128;   // never diagonal

        const unsigned short* __restrict__ gA = R + (size_t)row0 * D_DIM;
        const unsigned short* __restrict__ gB = R + (size_t)col0 * D_DIM;

        floatx4 acc[4][2] = {};

#define SSTAGE(d, kk) \
        { _Pragma("unroll") for (int i = 0; i < 2; ++i) { \
            __builtin_amdgcn_global_load_lds( \
              (AS1)(gA + (size_t)(wave * 16 + i * 8 + sR8) * D_DIM + (kk) + sS8 * 8), \
              (AS3)(&lds[d][0][(wave * 16 + i * 8) * 64]), 16, 0, 0); \
            __builtin_amdgcn_global_load_lds( \
              (AS1)(gB + (size_t)(wave * 16 + i * 8 + sR8) * D_DIM + (kk) + sS8 * 8), \
              (AS3)(&lds[d][1][(wave * 16 + i * 8) * 64]), 16, 0, 0); } }

        SSTAGE(0, 0)
        asm volatile("s_waitcnt vmcnt(0)" ::: "memory");
        __builtin_amdgcn_s_barrier();

        for (int kt = 0; kt < NKT64; ++kt) {
            const int buf = kt & 1;
            const unsigned short* As = &lds[buf][0][0];
            const unsigned short* Bs = &lds[buf][1][0];
            if (kt + 1 < NKT64) SSTAGE(buf ^ 1, (kt + 1) * 64)

            bf16x8 af[4][2], bf[2][2];
            #pragma unroll
            for (int mi = 0; mi < 4; ++mi) {
                const int r = (wm * 64 + mi * 16 + lm) * 64;
                af[mi][0] = *(const bf16x8*)(As + r + sk0);
                af[mi][1] = *(const bf16x8*)(As + r + sk1);
            }
            #pragma unroll
            for (int ni = 0; ni < 2; ++ni) {
                const int r = (wn * 32 + ni * 16 + lm) * 64;
                bf[ni][0] = *(const bf16x8*)(Bs + r + sk0);
                bf[ni][1] = *(const bf16x8*)(Bs + r + sk1);
            }
            __builtin_amdgcn_s_setprio(1);
            #pragma unroll
            for (int mi = 0; mi < 4; ++mi)
                #pragma unroll
                for (int ni = 0; ni < 2; ++ni) {
                    acc[mi][ni] = MFMA16(af[mi][0], bf[ni][0], acc[mi][ni], 0, 0, 0);
                    acc[mi][ni] = MFMA16(af[mi][1], bf[ni][1], acc[mi][ni], 0, 0, 0);
                }
            __builtin_amdgcn_s_setprio(0);

            asm volatile("s_waitcnt vmcnt(0)" ::: "memory");
            __builtin_amdgcn_s_barrier();
        }

        float* rowsum = (float*)&lds[0][0][0];   // [4][128]
        float* colsum = rowsum + 4 * 128;        // [2][128]
        float ecol[2] = {0.0f, 0.0f};
        #pragma unroll
        for (int mi = 0; mi < 4; ++mi) {
            const int rloc = wm * 64 + mi * 16 + lq * 4;
            #pragma unroll
            for (int reg = 0; reg < 4; ++reg) {
                const int gr = row0 + rloc + reg;
                float esum = 0.0f;
                #pragma unroll
                for (int ni = 0; ni < 2; ++ni) {
                    const int gc = col0 + wn * 32 + ni * 16 + lm;
                    float s = acc[mi][ni][reg] * INV_TEMP;
                    if (gc == gr + B_HALF) { pos[gr] = s; pos[gc] = s; }
                    float e = __expf(s);     // never on the main diagonal
                    esum += e;
                    ecol[ni] += e;
                }
                esum += __shfl_xor(esum, 1);
                esum += __shfl_xor(esum, 2);
                esum += __shfl_xor(esum, 4);
                esum += __shfl_xor(esum, 8);
                if (lm == 0) rowsum[wn * 128 + rloc + reg] = esum;
            }
        }
        #pragma unroll
        for (int ni = 0; ni < 2; ++ni) {
            ecol[ni] += __shfl_xor(ecol[ni], 16);
            ecol[ni] += __shfl_xor(ecol[ni], 32);
        }
        if (lq == 0) {
            #pragma unroll
            for (int ni = 0; ni < 2; ++ni)
                colsum[wm * 128 + wn * 32 + ni * 16 + lm] = ecol[ni];
        }
        __syncthreads();
        if (tid < 128) {
            float rs = rowsum[tid] + rowsum[128 + tid]
                     + rowsum[256 + tid] + rowsum[384 + tid];
            atomicAdd(&S[row0 + tid], rs);
            float cs = colsum[tid] + colsum[128 + tid];
            atomicAdd(&S[col0 + tid], cs);
        }
    }
}

// Kernel 3: single block; loss = mean(log1p(S * exp(-pos))).
__global__ __launch_bounds__(1024) void finalize_kernel(
    const float* __restrict__ S, const float* __restrict__ pos,
    float* __restrict__ out)
{
    const int tid = threadIdx.x;
    float local = 0.0f;
    #pragma unroll
    for (int i = 0; i < 8; ++i) {
        const int r = i * 1024 + tid;
        local += log1pf(S[r] * __expf(-pos[r]));
    }
    #pragma unroll
    for (int off = 32; off > 0; off >>= 1) local += __shfl_down(local, off);
    __shared__ float ws[16];
    if ((tid & 63) == 0) ws[tid >> 6] = local;
    __syncthreads();
    if (tid == 0) {
        float tot = 0.0f;
        #pragma unroll
        for (int i = 0; i < 16; ++i) tot += ws[i];
        out[0] = tot * (1.0f / 8192.0f);
    }
}

extern "C" void kernel_launch(void* const* d_in, const int* in_sizes, int n_in,
                              void* d_out, int out_size, void* d_ws, size_t ws_size,
                              hipStream_t stream)
{
    const float* z1 = (const float*)d_in[0];
    const float* z2 = (const float*)d_in[1];
    float* out = (float*)d_out;
    char* ws = (char*)d_ws;
    unsigned short* R = (unsigned short*)ws;                        // 16 MiB bf16 reps
    float* pos = (float*)(ws + (size_t)16 * 1024 * 1024);           // 32 KiB [8192]
    float* S   = (float*)(ws + (size_t)16 * 1024 * 1024 + 65536);   // 32 KiB [8192]

    normalize_kernel<<<2048, 256, 0, stream>>>(z1, z2, R, S);
    gemm_lse_kernel<<<NBLK, 512, 0, stream>>>(R, S, pos);
    finalize_kernel<<<1, 1024, 0, stream>>>(S, pos, out);
}